// Round 9
// baseline (87.219 us; speedup 1.0000x reference)
//
#include <hip/hip_runtime.h>
#include <hip/hip_bf16.h>
#include <cstdint>
#include <cstddef>

#define NB 2048
#define NT 200
#define ND 64
#define NH1 128
#define NH2 64
#define NTILES 7
#define NTP 224

typedef __bf16 bf16x8 __attribute__((ext_vector_type(8)));
typedef float f32x4 __attribute__((ext_vector_type(4)));

#define MFMA16(A, Bv, C) __builtin_amdgcn_mfma_f32_16x16x32_bf16((A), (Bv), (C), 0, 0, 0)

union BF8u { __bf16 b[8]; bf16x8 v; uint4 u4; };

// sum over the 16-lane DPP row (circulant rotate-add); result in every lane
template<int N>
__device__ __forceinline__ float row_ror_add(float v) {
    int r = __builtin_amdgcn_update_dpp(0, __builtin_bit_cast(int, v),
                                        0x120 | N, 0xF, 0xF, false);
    return v + __builtin_bit_cast(float, r);
}

// Raw workgroup barrier: drains LDS ops (visibility) but NOT global loads,
// so register-resident prefetches stay in flight across it. (rule #18 fencing)
__device__ __forceinline__ void bar_sync() {
    __builtin_amdgcn_sched_barrier(0);
    asm volatile("s_waitcnt lgkmcnt(0)" ::: "memory");
    __builtin_amdgcn_s_barrier();
    __builtin_amdgcn_sched_barrier(0);
}

// prep: Qp[c][j] = (W1q+W1d)[c][j]; AbT[j][c] = (W1k-W1d)[c][j];
//       PT[j][c] = W1prod[c][j];    W2t[h2][k] = bf16(W2[k][h2])
__global__ void prep_kernel(const float* __restrict__ W1, const float* __restrict__ W2,
                            float* __restrict__ Qp, float* __restrict__ AbT,
                            float* __restrict__ PT, __bf16* __restrict__ W2t) {
    int tid = blockIdx.x * blockDim.x + threadIdx.x;
    if (tid < 64 * NH1) {
        int c = tid >> 7, j = tid & 127;
        Qp[tid] = W1[c * NH1 + j] + W1[(128 + c) * NH1 + j];
        int jj = tid >> 6, cc = tid & 63;
        AbT[tid] = W1[(64 + cc) * NH1 + jj] - W1[(128 + cc) * NH1 + jj];
        PT[tid]  = W1[(192 + cc) * NH1 + jj];
        int j2 = tid >> 7, k = tid & 127;
        W2t[tid] = (__bf16)W2[k * NH2 + j2];
    }
}

// LDS pool (31872 B; 4-5 blocks/CU):
//  [0,     4608)  KHI0[32][72] bf16   (aliased by REDS[16][72] f32 in epilogue)
//  [4608,  9216)  KHI1[32][72] bf16
//  [9216, 17920)  H10 [32][136] bf16
//  [17920,26624)  H11 [32][136] bf16
//  [26624,30208)  SP  [4][224] f32
//  [30208,31104)  MASKF[224] f32
//  [31104,31360)  QS  [64] f32
//  [31360,31872)  QHS [128] f32
__global__ __launch_bounds__(256, 4)
void attn_main(const float* __restrict__ query, const float* __restrict__ key,
               const float* __restrict__ value, const int* __restrict__ mask,
               const float* __restrict__ b1, const float* __restrict__ b2,
               const float* __restrict__ Wo,
               const float* __restrict__ Qp, const float* __restrict__ AbT,
               const float* __restrict__ PT, const __bf16* __restrict__ W2t,
               float* __restrict__ out)
{
    __shared__ __align__(16) char smem[31872];
    auto KHI0 = (__bf16(*)[72])(smem);
    auto KHI1 = (__bf16(*)[72])(smem + 4608);
    auto H10  = (__bf16(*)[136])(smem + 9216);
    auto H11  = (__bf16(*)[136])(smem + 17920);
    auto SP   = (float(*)[NTP])(smem + 26624);
    float* MASKF = (float*)(smem + 30208);
    float* QS  = (float*)(smem + 31104);
    float* QHS = (float*)(smem + 31360);
    auto REDS = (float(*)[72])(smem);          // alias KHI (dead after main loop)

    const int b = blockIdx.x;
    const int tid = threadIdx.x;
    const int lane = tid & 63;
    const int wave = tid >> 6;
    const int jn = lane & 15;
    const int g4 = lane >> 4;
    const int g8 = g4 * 8;
    const int tg = tid >> 4;     // 0..15 : V/consume row group
    const int dq = tid & 15;     // 0..15 : V col group

    // ---- k-tile staging: coalesced loads, DEPTH-2 register prefetch ----
    const int r_st = tid >> 3;            // row 0..31
    const int c0   = (tid & 7) * 8;       // col 0..56
    const float* kp_base = key + (size_t)b * NT * ND + c0;
    float4 pf[2][2];                      // [tile&1][half]; static indices post-unroll

    {   // issue k(0), k(1) immediately: in flight across the whole prologue
        const float* kp0 = kp_base + (size_t)r_st * ND;
        pf[0][0] = *(const float4*)(kp0);
        pf[0][1] = *(const float4*)(kp0 + 4);
        const float* kp1 = kp_base + (size_t)(32 + r_st) * ND;
        pf[1][0] = *(const float4*)(kp1);
        pf[1][1] = *(const float4*)(kp1 + 4);
    }

    if (tid < ND) QS[tid] = query[(size_t)b * ND + tid];
    if (tid < NTP) MASKF[tid] = (tid < NT && mask[(size_t)b * NT + tid] != 0) ? 1.f : 0.f;
    bar_sync();                            // QS, MASKF visible

    // qh = b1 + q.(W1q+W1d), 4-way split accumulators
    if (tid < NH1) {
        float a0 = 0.f, a1 = 0.f, a2 = 0.f, a3 = 0.f;
        #pragma unroll
        for (int c = 0; c < ND; c += 4) {
            a0 = fmaf(QS[c],     Qp[c * NH1 + tid],       a0);
            a1 = fmaf(QS[c + 1], Qp[(c + 1) * NH1 + tid], a1);
            a2 = fmaf(QS[c + 2], Qp[(c + 2) * NH1 + tid], a2);
            a3 = fmaf(QS[c + 3], Qp[(c + 3) * NH1 + tid], a3);
        }
        QHS[tid] = b1[tid] + ((a0 + a1) + (a2 + a3));
    }

    // GEMM1 B-frags: B_b[c][j] = AbT[j][c] + q[c]*PT[j][c], bf16 hi+lo, registers.
    bf16x8 g1_bhi[2][2], g1_blo[2][2];
    const int jown = wave * 32;
    #pragma unroll
    for (int n = 0; n < 2; ++n) {
        const int j = jown + n * 16 + jn;
        #pragma unroll
        for (int kk = 0; kk < 2; ++kk) {
            const float* ab = AbT + j * ND + kk * 32 + g8;
            const float* pt = PT  + j * ND + kk * 32 + g8;
            float4 a0 = *(const float4*)ab, a1 = *(const float4*)(ab + 4);
            float4 p0 = *(const float4*)pt, p1 = *(const float4*)(pt + 4);
            const float va[8] = {a0.x,a0.y,a0.z,a0.w,a1.x,a1.y,a1.z,a1.w};
            const float vp[8] = {p0.x,p0.y,p0.z,p0.w,p1.x,p1.y,p1.z,p1.w};
            BF8u vh, vl;
            #pragma unroll
            for (int e = 0; e < 8; ++e) {
                const int c = kk * 32 + g8 + e;
                float v = fmaf(QS[c], vp[e], va[e]);
                __bf16 hi = (__bf16)v;
                vh.b[e] = hi;
                vl.b[e] = (__bf16)(v - (float)hi);
            }
            g1_bhi[n][kk] = vh.v;
            g1_blo[n][kk] = vl.v;
        }
    }
    // GEMM2 B-frags (plain bf16 W2t)
    bf16x8 g2_w[4];
    {
        const int j2 = wave * 16 + jn;
        #pragma unroll
        for (int kk = 0; kk < 4; ++kk)
            g2_w[kk] = *(const bf16x8*)(W2t + j2 * NH1 + kk * 32 + g8);
    }
    bar_sync();                            // QHS visible
    const float qh0 = QHS[jown + jn];
    const float qh1 = QHS[jown + 16 + jn];
    const float b2j = b2[wave * 16 + jn];
    const float woj = Wo[wave * 16 + jn];

    // ---- fused-V pipeline state ----
    const float* vbase = value + (size_t)b * NT * ND + dq * 4;
    float4 vv0{}, vv1{};                  // V rows of tile (consumed 1 iter after load)
    float oa0 = 0.f, oa1 = 0.f, oa2 = 0.f, oa3 = 0.f, den = 0.f;

    // ---- fully-unrolled pipelined main loop: one RAW barrier per iteration ----
    // iter ti: pre : publish k(ti)->K[ti&1], publish h1(ti-1)->H1[(ti-1)&1]
    //          bar : lgkmcnt(0) + s_barrier (global loads stay in flight!)
    //          post: issue k(ti+2); GEMM1(ti); GEMM2(ti-1)->SP;
    //                consume(ti-2): exp(SP)+V-accum; load V(ti-1)
    f32x4 accc[2][2];
    #pragma unroll
    for (int ti = 0; ti <= NTILES; ++ti) {
        __bf16 (*KCUR)[72]   = (ti & 1) ? KHI1 : KHI0;
        __bf16 (*H1CUR)[136] = ((ti + 1) & 1) ? H11 : H10;   // == (ti-1)&1

        if (ti < NTILES) {                 // publish k(ti) (counted vmcnt at use)
            const int bi = ti & 1;
            const float vals[8] = {pf[bi][0].x, pf[bi][0].y, pf[bi][0].z, pf[bi][0].w,
                                   pf[bi][1].x, pf[bi][1].y, pf[bi][1].z, pf[bi][1].w};
            BF8u ph;
            #pragma unroll
            for (int i = 0; i < 8; ++i) ph.b[i] = (__bf16)vals[i];
            *(uint4*)(&KCUR[r_st][c0]) = ph.u4;
        }
        if (ti > 0) {                      // publish h1(ti-1) from carried accs
            #pragma unroll
            for (int mt = 0; mt < 2; ++mt)
            #pragma unroll
            for (int n = 0; n < 2; ++n) {
                const float qhj = n ? qh1 : qh0;
                const int j = jown + n * 16 + jn;
                #pragma unroll
                for (int r = 0; r < 4; ++r)
                    H1CUR[mt * 16 + g4 * 4 + r][j] =
                        (__bf16)fmaxf(accc[mt][n][r] + qhj, 0.f);
            }
        }
        bar_sync();

        if (ti + 2 < NTILES) {             // issue k(ti+2): ~2 iteration bodies to land
            const int bi = ti & 1;
            int t = (ti + 2) * 32 + r_st;
            t = t < NT ? t : NT - 1;
            const float* kp = kp_base + (size_t)t * ND;
            pf[bi][0] = *(const float4*)(kp);
            pf[bi][1] = *(const float4*)(kp + 4);
        }
        if (ti < NTILES) {                 // GEMM1(ti): k @ B_b -> accc
            #pragma unroll
            for (int mt = 0; mt < 2; ++mt) {
                const int arow = mt * 16 + jn;
                const bf16x8 a0 = *(const bf16x8*)(&KCUR[arow][g8]);
                const bf16x8 a1 = *(const bf16x8*)(&KCUR[arow][32 + g8]);
                #pragma unroll
                for (int n = 0; n < 2; ++n) {
                    f32x4 ac = {0.f, 0.f, 0.f, 0.f};
                    ac = MFMA16(a0, g1_bhi[n][0], ac);
                    ac = MFMA16(a1, g1_bhi[n][1], ac);
                    ac = MFMA16(a0, g1_blo[n][0], ac);
                    ac = MFMA16(a1, g1_blo[n][1], ac);
                    accc[mt][n] = ac;
                }
            }
        }
        if (ti > 0) {                      // GEMM2(ti-1) + score -> SP
            const int t0 = (ti - 1) * 32;
            #pragma unroll
            for (int mt = 0; mt < 2; ++mt) {
                const int arow = mt * 16 + jn;
                const bf16x8 h0v = *(const bf16x8*)(&H1CUR[arow][g8]);
                const bf16x8 h1v = *(const bf16x8*)(&H1CUR[arow][32 + g8]);
                const bf16x8 h2v = *(const bf16x8*)(&H1CUR[arow][64 + g8]);
                const bf16x8 h3v = *(const bf16x8*)(&H1CUR[arow][96 + g8]);
                f32x4 cA = {0.f,0.f,0.f,0.f}, cB = {0.f,0.f,0.f,0.f};
                cA = MFMA16(h0v, g2_w[0], cA);
                cB = MFMA16(h1v, g2_w[1], cB);
                cA = MFMA16(h2v, g2_w[2], cA);
                cB = MFMA16(h3v, g2_w[3], cB);
                #pragma unroll
                for (int r = 0; r < 4; ++r) {
                    float v = fmaxf(cA[r] + cB[r] + b2j, 0.f) * woj;
                    v = row_ror_add<8>(v);
                    v = row_ror_add<4>(v);
                    v = row_ror_add<2>(v);
                    v = row_ror_add<1>(v);
                    if (jn == 0) SP[wave][t0 + mt * 16 + g4 * 4 + r] = v;
                }
            }
        }
        if (ti >= 2) {                     // consume tile ti-2: e=mask*exp(s); O += e*V
            const int r0 = (ti - 2) * 32 + tg, r1 = r0 + 16;
            const float s0 = SP[0][r0] + SP[1][r0] + SP[2][r0] + SP[3][r0];
            const float s1 = SP[0][r1] + SP[1][r1] + SP[2][r1] + SP[3][r1];
            const float e0 = MASKF[r0] * __expf(s0);
            const float e1 = MASKF[r1] * __expf(s1);
            oa0 = fmaf(e0, vv0.x, fmaf(e1, vv1.x, oa0));
            oa1 = fmaf(e0, vv0.y, fmaf(e1, vv1.y, oa1));
            oa2 = fmaf(e0, vv0.z, fmaf(e1, vv1.z, oa2));
            oa3 = fmaf(e0, vv0.w, fmaf(e1, vv1.w, oa3));
            den += e0 + e1;
        }
        if (ti >= 1) {                     // load V(ti-1), consumed next iteration
            int t0v = (ti - 1) * 32 + tg;      t0v = t0v < NT ? t0v : NT - 1;
            int t1v = (ti - 1) * 32 + tg + 16; t1v = t1v < NT ? t1v : NT - 1;
            vv0 = *(const float4*)(vbase + (size_t)t0v * ND);
            vv1 = *(const float4*)(vbase + (size_t)t1v * ND);
        }
    }

    bar_sync();                            // SP(6) visible; K buffers dead
    {   // consume last tile (6) with V(6) loaded at ti=7
        const int r0 = (NTILES - 1) * 32 + tg, r1 = r0 + 16;
        const float s0 = SP[0][r0] + SP[1][r0] + SP[2][r0] + SP[3][r0];
        const float s1 = SP[0][r1] + SP[1][r1] + SP[2][r1] + SP[3][r1];
        const float e0 = MASKF[r0] * __expf(s0);
        const float e1 = MASKF[r1] * __expf(s1);
        oa0 = fmaf(e0, vv0.x, fmaf(e1, vv1.x, oa0));
        oa1 = fmaf(e0, vv0.y, fmaf(e1, vv1.y, oa1));
        oa2 = fmaf(e0, vv0.z, fmaf(e1, vv1.z, oa2));
        oa3 = fmaf(e0, vv0.w, fmaf(e1, vv1.w, oa3));
        den += e0 + e1;
    }
    REDS[tg][dq*4+0] = oa0; REDS[tg][dq*4+1] = oa1;
    REDS[tg][dq*4+2] = oa2; REDS[tg][dq*4+3] = oa3;
    if (dq == 0) REDS[tg][64] = den;
    bar_sync();

    if (tid < ND) {
        float s = 0.f, d = 0.f;
        #pragma unroll
        for (int g = 0; g < 16; ++g) { s += REDS[g][tid]; d += REDS[g][64]; }
        out[(size_t)b * ND + tid] = s / d;
    }
}

extern "C" void kernel_launch(void* const* d_in, const int* in_sizes, int n_in,
                              void* d_out, int out_size, void* d_ws, size_t ws_size,
                              hipStream_t stream) {
    const float* query = (const float*)d_in[0];
    const float* key   = (const float*)d_in[1];
    const float* value = (const float*)d_in[2];
    const int*   maskp = (const int*)d_in[3];
    const float* W1    = (const float*)d_in[4];
    const float* b1    = (const float*)d_in[5];
    const float* W2    = (const float*)d_in[6];
    const float* b2    = (const float*)d_in[7];
    const float* Wo    = (const float*)d_in[8];
    float* out = (float*)d_out;

    float* Qp  = (float*)d_ws;                 // 64*128 f32
    float* AbT = Qp + 64 * NH1;                // 128*64 f32
    float* PT  = AbT + NH1 * ND;               // 128*64 f32
    __bf16* W2t = (__bf16*)(PT + NH1 * ND);    // 64*128 bf16

    prep_kernel<<<32, 256, 0, stream>>>(W1, W2, Qp, AbT, PT, W2t);
    attn_main<<<NB, 256, 0, stream>>>(query, key, value, maskp, b1, b2, Wo,
                                      Qp, AbT, PT, W2t, out);
}

// Round 10
// 54.197 us; speedup vs baseline: 1.6093x; 1.6093x over previous
//
#include <hip/hip_runtime.h>
#include <hip/hip_bf16.h>
#include <cstdint>
#include <cstddef>

#define NB 2048
#define NT 200
#define ND 64
#define NH1 128
#define NH2 64
#define NTILES 7
#define NTP 224

typedef __bf16 bf16x8 __attribute__((ext_vector_type(8)));
typedef float f32x4 __attribute__((ext_vector_type(4)));

#define MFMA16(A, Bv, C) __builtin_amdgcn_mfma_f32_16x16x32_bf16((A), (Bv), (C), 0, 0, 0)

union BF8u { __bf16 b[8]; bf16x8 v; uint4 u4; };
union BF4u { __bf16 b[4]; uint2 u2; };

// sum over the 16-lane DPP row (circulant rotate-add); result in every lane
template<int N>
__device__ __forceinline__ float row_ror_add(float v) {
    int r = __builtin_amdgcn_update_dpp(0, __builtin_bit_cast(int, v),
                                        0x120 | N, 0xF, 0xF, false);
    return v + __builtin_bit_cast(float, r);
}

// Raw workgroup barrier: drains LDS ops (visibility) but NOT global loads,
// so register-resident prefetches stay in flight across it. (rule #18 fencing)
__device__ __forceinline__ void bar_sync() {
    __builtin_amdgcn_sched_barrier(0);
    asm volatile("s_waitcnt lgkmcnt(0)" ::: "memory");
    __builtin_amdgcn_s_barrier();
    __builtin_amdgcn_sched_barrier(0);
}

// prep: Qp[c][j] = (W1q+W1d)[c][j]; AbT[j][c] = (W1k-W1d)[c][j];
//       PT[j][c] = W1prod[c][j];    W2t[h2][k] = bf16(W2[k][h2])
__global__ void prep_kernel(const float* __restrict__ W1, const float* __restrict__ W2,
                            float* __restrict__ Qp, float* __restrict__ AbT,
                            float* __restrict__ PT, __bf16* __restrict__ W2t) {
    int tid = blockIdx.x * blockDim.x + threadIdx.x;
    if (tid < 64 * NH1) {
        int c = tid >> 7, j = tid & 127;
        Qp[tid] = W1[c * NH1 + j] + W1[(128 + c) * NH1 + j];
        int jj = tid >> 6, cc = tid & 63;
        AbT[tid] = W1[(64 + cc) * NH1 + jj] - W1[(128 + cc) * NH1 + jj];
        PT[tid]  = W1[(192 + cc) * NH1 + jj];
        int j2 = tid >> 7, k = tid & 127;
        W2t[tid] = (__bf16)W2[k * NH2 + j2];
    }
}

// LDS pool (30976 B; r8-identical map):
//  [0,     4608)  KHI0[32][72] bf16   (aliased by SCORES[224] f32 after main loop)
//  [4608,  9216)  KHI1[32][72] bf16
//  [9216, 17920)  H10 [32][136] bf16  (aliased by REDS[16][72] f32 in epilogue)
//  [17920,26624)  H11 [32][136] bf16
//  [26624,30208)  SP  [4][224] f32
//  [30208,30464)  QS  [64] f32
//  [30464,30976)  QHS [128] f32
__global__ __launch_bounds__(256, 4)
void attn_main(const float* __restrict__ query, const float* __restrict__ key,
               const float* __restrict__ value, const int* __restrict__ mask,
               const float* __restrict__ b1, const float* __restrict__ b2,
               const float* __restrict__ Wo,
               const float* __restrict__ Qp, const float* __restrict__ AbT,
               const float* __restrict__ PT, const __bf16* __restrict__ W2t,
               float* __restrict__ out)
{
    __shared__ __align__(16) char smem[30976];
    auto KHI0 = (__bf16(*)[72])(smem);
    auto KHI1 = (__bf16(*)[72])(smem + 4608);
    auto H10  = (__bf16(*)[136])(smem + 9216);
    auto H11  = (__bf16(*)[136])(smem + 17920);
    auto SP   = (float(*)[NTP])(smem + 26624);
    float* QS  = (float*)(smem + 30208);
    float* QHS = (float*)(smem + 30464);
    float* SCORES = (float*)(smem);            // alias KHI0 (dead after main loop)
    auto REDS = (float(*)[72])(smem + 9216);   // alias H10  (dead after main loop)

    const int b = blockIdx.x;
    const int tid = threadIdx.x;
    const int lane = tid & 63;
    const int wave = tid >> 6;
    const int jn = lane & 15;
    const int g4 = lane >> 4;
    const int g8 = g4 * 8;

    // ---- k-tile staging: coalesced loads, DEPTH-2 register prefetch ----
    const int r_st = tid >> 3;            // row 0..31
    const int c0   = (tid & 7) * 8;       // col 0..56
    const float* kp_base = key + (size_t)b * NT * ND + c0;
    float4 pf[2][2];                      // [tile&1][half]; static indices post-unroll

    {   // issue k(0), k(1) immediately: in flight across the whole prologue
        const float* kp0 = kp_base + (size_t)r_st * ND;
        pf[0][0] = *(const float4*)(kp0);
        pf[0][1] = *(const float4*)(kp0 + 4);
        const float* kp1 = kp_base + (size_t)(32 + r_st) * ND;
        pf[1][0] = *(const float4*)(kp1);
        pf[1][1] = *(const float4*)(kp1 + 4);
    }

    if (tid < ND) QS[tid] = query[(size_t)b * ND + tid];
    int mk = 0;
    if (tid < NT) mk = mask[(size_t)b * NT + tid];
    bar_sync();                            // QS visible

    // qh = b1 + q.(W1q+W1d), 4-way split accumulators
    if (tid < NH1) {
        float a0 = 0.f, a1 = 0.f, a2 = 0.f, a3 = 0.f;
        #pragma unroll
        for (int c = 0; c < ND; c += 4) {
            a0 = fmaf(QS[c],     Qp[c * NH1 + tid],       a0);
            a1 = fmaf(QS[c + 1], Qp[(c + 1) * NH1 + tid], a1);
            a2 = fmaf(QS[c + 2], Qp[(c + 2) * NH1 + tid], a2);
            a3 = fmaf(QS[c + 3], Qp[(c + 3) * NH1 + tid], a3);
        }
        QHS[tid] = b1[tid] + ((a0 + a1) + (a2 + a3));
    }

    // GEMM1 A-frags (swapped): A[j][c] = B_b[c][j] = AbT[j][c] + q[c]*PT[j][c],
    // bf16 hi only (h1 is bf16-quantized at the LDS store anyway).
    bf16x8 g1_b[2][2];
    const int jown = wave * 32;
    #pragma unroll
    for (int n = 0; n < 2; ++n) {
        const int j = jown + n * 16 + jn;
        #pragma unroll
        for (int kk = 0; kk < 2; ++kk) {
            const float* ab = AbT + j * ND + kk * 32 + g8;
            const float* pt = PT  + j * ND + kk * 32 + g8;
            float4 a0 = *(const float4*)ab, a1 = *(const float4*)(ab + 4);
            float4 p0 = *(const float4*)pt, p1 = *(const float4*)(pt + 4);
            const float va[8] = {a0.x,a0.y,a0.z,a0.w,a1.x,a1.y,a1.z,a1.w};
            const float vp[8] = {p0.x,p0.y,p0.z,p0.w,p1.x,p1.y,p1.z,p1.w};
            BF8u vh;
            #pragma unroll
            for (int e = 0; e < 8; ++e) {
                const int c = kk * 32 + g8 + e;
                vh.b[e] = (__bf16)fmaf(QS[c], vp[e], va[e]);
            }
            g1_b[n][kk] = vh.v;
        }
    }
    // GEMM2 B-frags (plain bf16 W2t)
    bf16x8 g2_w[4];
    {
        const int j2 = wave * 16 + jn;
        #pragma unroll
        for (int kk = 0; kk < 4; ++kk)
            g2_w[kk] = *(const bf16x8*)(W2t + j2 * NH1 + kk * 32 + g8);
    }
    bar_sync();                            // QHS visible

    // per-lane qh for the swapped C-layout: j = jown + n*16 + g4*4 + r
    float qh4[2][4];
    {
        const float4 qa = *(const float4*)(QHS + jown + g4 * 4);
        const float4 qb = *(const float4*)(QHS + jown + 16 + g4 * 4);
        qh4[0][0] = qa.x; qh4[0][1] = qa.y; qh4[0][2] = qa.z; qh4[0][3] = qa.w;
        qh4[1][0] = qb.x; qh4[1][1] = qb.y; qh4[1][2] = qb.z; qh4[1][3] = qb.w;
    }
    const float b2j = b2[wave * 16 + jn];
    const float woj = Wo[wave * 16 + jn];

    // ---- fully-unrolled pipelined main loop: one RAW barrier per iteration ----
    // iter ti: pre : publish k(ti)->K[ti&1], publish h1(ti-1)->H1[(ti-1)&1]
    //          bar : lgkmcnt(0) + s_barrier (global loads stay in flight!)
    //          post: issue k(ti+2)->pf[ti&1]; GEMM1(ti)->accc; GEMM2(ti-1)->SP
    // GEMM1 is operand-swapped: accc[mt][n] = h1^T tile; lane holds
    // (t = mt*16+jn, j = jown+n*16+g4*4+r) -> h1 publish is 4x ds_write_b64.
    f32x4 accc[2][2];
    #pragma unroll
    for (int ti = 0; ti <= NTILES; ++ti) {
        __bf16 (*KCUR)[72]   = (ti & 1) ? KHI1 : KHI0;
        __bf16 (*H1CUR)[136] = ((ti + 1) & 1) ? H11 : H10;   // == (ti-1)&1

        if (ti < NTILES) {                 // publish k(ti) (counted vmcnt at use)
            const int bi = ti & 1;
            const float vals[8] = {pf[bi][0].x, pf[bi][0].y, pf[bi][0].z, pf[bi][0].w,
                                   pf[bi][1].x, pf[bi][1].y, pf[bi][1].z, pf[bi][1].w};
            BF8u ph;
            #pragma unroll
            for (int i = 0; i < 8; ++i) ph.b[i] = (__bf16)vals[i];
            *(uint4*)(&KCUR[r_st][c0]) = ph.u4;
        }
        if (ti > 0) {                      // publish h1(ti-1): 4x b64 per lane
            #pragma unroll
            for (int mt = 0; mt < 2; ++mt) {
                const int trow = mt * 16 + jn;
                #pragma unroll
                for (int n = 0; n < 2; ++n) {
                    BF4u pk;
                    #pragma unroll
                    for (int r = 0; r < 4; ++r)
                        pk.b[r] = (__bf16)fmaxf(accc[mt][n][r] + qh4[n][r], 0.f);
                    *(uint2*)(&H1CUR[trow][jown + n * 16 + g4 * 4]) = pk.u2;
                }
            }
        }
        bar_sync();

        if (ti + 2 < NTILES) {             // issue k(ti+2): ~2 iteration bodies to land
            const int bi = ti & 1;
            int t = (ti + 2) * 32 + r_st;
            t = t < NT ? t : NT - 1;
            const float* kp = kp_base + (size_t)t * ND;
            pf[bi][0] = *(const float4*)(kp);
            pf[bi][1] = *(const float4*)(kp + 4);
        }
        if (ti < NTILES) {                 // GEMM1(ti) swapped: B_b^T @ k^T -> accc
            #pragma unroll
            for (int mt = 0; mt < 2; ++mt) {
                const int arow = mt * 16 + jn;
                const bf16x8 k0 = *(const bf16x8*)(&KCUR[arow][g8]);
                const bf16x8 k1 = *(const bf16x8*)(&KCUR[arow][32 + g8]);
                #pragma unroll
                for (int n = 0; n < 2; ++n) {
                    f32x4 ac = {0.f, 0.f, 0.f, 0.f};
                    ac = MFMA16(g1_b[n][0], k0, ac);
                    ac = MFMA16(g1_b[n][1], k1, ac);
                    accc[mt][n] = ac;
                }
            }
        }
        if (ti > 0) {                      // GEMM2(ti-1) + score -> SP
            const int t0 = (ti - 1) * 32;
            #pragma unroll
            for (int mt = 0; mt < 2; ++mt) {
                const int arow = mt * 16 + jn;
                const bf16x8 h0v = *(const bf16x8*)(&H1CUR[arow][g8]);
                const bf16x8 h1v = *(const bf16x8*)(&H1CUR[arow][32 + g8]);
                const bf16x8 h2v = *(const bf16x8*)(&H1CUR[arow][64 + g8]);
                const bf16x8 h3v = *(const bf16x8*)(&H1CUR[arow][96 + g8]);
                f32x4 cA = {0.f,0.f,0.f,0.f}, cB = {0.f,0.f,0.f,0.f};
                cA = MFMA16(h0v, g2_w[0], cA);
                cB = MFMA16(h1v, g2_w[1], cB);
                cA = MFMA16(h2v, g2_w[2], cA);
                cB = MFMA16(h3v, g2_w[3], cB);
                #pragma unroll
                for (int r = 0; r < 4; ++r) {
                    float v = fmaxf(cA[r] + cB[r] + b2j, 0.f) * woj;
                    v = row_ror_add<8>(v);
                    v = row_ror_add<4>(v);
                    v = row_ror_add<2>(v);
                    v = row_ror_add<1>(v);
                    if (jn == 0) SP[wave][t0 + mt * 16 + g4 * 4 + r] = v;
                }
            }
        }
    }

    // ---- V prefetch (first two rows/thread) — survives the raw barriers ----
    const int tg = tid >> 4;
    const int dq = tid & 15;
    const float* vbase = value + (size_t)b * NT * ND + dq * 4;
    const float4 vv0 = *(const float4*)(vbase + (size_t)tg * ND);
    const float4 vv1 = *(const float4*)(vbase + (size_t)(tg + 16) * ND);

    bar_sync();                            // all SP visible; K/H1 buffers dead

    // ---- softmax numerator (no max-sub: |s| small, fp32 exp safe) ----
    if (tid < NTP) {
        const float sc = SP[0][tid] + SP[1][tid] + SP[2][tid] + SP[3][tid];
        SCORES[tid] = (tid < NT && mk != 0) ? __expf(sc) : 0.f;
    }
    bar_sync();                            // SCORES ready

    // ---- out = (e @ V) / sum(e), denominator fused ----
    {
        const float e0 = SCORES[tg], e1 = SCORES[tg + 16];
        float oa0 = fmaf(e1, vv1.x, e0 * vv0.x);
        float oa1 = fmaf(e1, vv1.y, e0 * vv0.y);
        float oa2 = fmaf(e1, vv1.z, e0 * vv0.z);
        float oa3 = fmaf(e1, vv1.w, e0 * vv0.w);
        float den = e0 + e1;
        #pragma unroll 4
        for (int t = tg + 32; t < NT; t += 16) {
            const float e = SCORES[t];
            const float4 v4 = *(const float4*)(vbase + (size_t)t * ND);
            oa0 = fmaf(e, v4.x, oa0); oa1 = fmaf(e, v4.y, oa1);
            oa2 = fmaf(e, v4.z, oa2); oa3 = fmaf(e, v4.w, oa3);
            den += e;
        }
        REDS[tg][dq*4+0] = oa0; REDS[tg][dq*4+1] = oa1;
        REDS[tg][dq*4+2] = oa2; REDS[tg][dq*4+3] = oa3;
        if (dq == 0) REDS[tg][64] = den;
    }
    bar_sync();

    if (tid < ND) {
        float s = 0.f, den = 0.f;
        #pragma unroll
        for (int g = 0; g < 16; ++g) { s += REDS[g][tid]; den += REDS[g][64]; }
        out[(size_t)b * ND + tid] = s / den;
    }
}

extern "C" void kernel_launch(void* const* d_in, const int* in_sizes, int n_in,
                              void* d_out, int out_size, void* d_ws, size_t ws_size,
                              hipStream_t stream) {
    const float* query = (const float*)d_in[0];
    const float* key   = (const float*)d_in[1];
    const float* value = (const float*)d_in[2];
    const int*   maskp = (const int*)d_in[3];
    const float* W1    = (const float*)d_in[4];
    const float* b1    = (const float*)d_in[5];
    const float* W2    = (const float*)d_in[6];
    const float* b2    = (const float*)d_in[7];
    const float* Wo    = (const float*)d_in[8];
    float* out = (float*)d_out;

    float* Qp  = (float*)d_ws;                 // 64*128 f32
    float* AbT = Qp + 64 * NH1;                // 128*64 f32
    float* PT  = AbT + NH1 * ND;               // 128*64 f32
    __bf16* W2t = (__bf16*)(PT + NH1 * ND);    // 64*128 bf16

    prep_kernel<<<32, 256, 0, stream>>>(W1, W2, Qp, AbT, PT, W2t);
    attn_main<<<NB, 256, 0, stream>>>(query, key, value, maskp, b1, b2, Wo,
                                      Qp, AbT, PT, W2t, out);
}